// Round 4
// baseline (428.725 us; speedup 1.0000x reference)
//
#include <hip/hip_runtime.h>

// Trilinear interpolation of 2M points into a 128x128x128x16 fp32 grid.
// v5: v4 hierarchical binning +
//  - coarse cursors/regions sharded 8-ways by blockIdx&7 (XCD round-robin)
//    so same-address atomic chains never bounce lines across XCDs.
//  - interp out-stores are CACHED (not nontemporal): each 128B out line gets
//    exactly 2 random 64B point-writes; the shared 256MB Infinity Cache can
//    merge them into full-line writebacks (NT forced 64B partials at 0.95TB/s,
//    which was the entire interp bottleneck: 125MB/133us).
// Results bit-identical to v1 (same op order everywhere).

#define DD 128
#define NBX 16                      // fine buckets per dim (8^3 voxels)
#define NB  (NBX * NBX * NBX)       // 4096 fine buckets
#define NCX 4                       // coarse buckets per dim (32^3 voxels)
#define NC  (NCX * NCX * NCX)       // 64 coarse buckets
#define NSH 8                       // coarse shards (one per XCD via blockIdx&7)
#define NFPC 64                     // fine buckets per coarse (4^3)
#define CAPC 4480                   // per-(coarse,shard) capacity (mean 3906, +9 sigma)
#define CAPF 560                    // fine region capacity (mean 488, +3.2 sigma)
#define CAPL 48                     // LDS staging records per bucket
#define FLUSH_T 32                  // flush threshold (>=512B per flush)
#define CCUR_STRIDE 16              // coarse cursor padding (64B)
#define FCUR_STRIDE 4               // fine cursor padding (16B)
#define SCAT_BLOCKS 512

typedef float fvec4 __attribute__((ext_vector_type(4)));

__device__ __forceinline__ float4 lerp4(float4 a, float4 b, float t) {
    return make_float4(fmaf(b.x - a.x, t, a.x),
                       fmaf(b.y - a.y, t, a.y),
                       fmaf(b.z - a.z, t, a.z),
                       fmaf(b.w - a.w, t, a.w));
}

__device__ __forceinline__ int clampi(int v, int lo, int hi) {
    return min(max(v, lo), hi);
}

// Direct (global-gather) path - identical op order to verified v1.
__device__ __forceinline__ float4 trilerp_point(const float4* __restrict__ values,
                                                float x, float y, float z, int c4) {
    float fx = floorf(x), fy = floorf(y), fz = floorf(z);
    int x0 = clampi((int)fx, 0, DD - 1);
    int y0 = clampi((int)fy, 0, DD - 1);
    int z0 = clampi((int)fz, 0, DD - 1);
    int x1 = min(x0 + 1, DD - 1);
    int y1 = min(y0 + 1, DD - 1);
    int z1 = min(z0 + 1, DD - 1);

    float xd = x - (float)x0;
    float yd = y - (float)y0;
    float zd = z - (float)z0;

    #define VIDX(xi, yi, zi) ((((((xi) << 7) + (yi)) << 7) + (zi)) * 4 + c4)
    float4 c000 = values[VIDX(x0, y0, z0)];
    float4 c001 = values[VIDX(x0, y0, z1)];
    float4 c010 = values[VIDX(x0, y1, z0)];
    float4 c011 = values[VIDX(x0, y1, z1)];
    float4 c100 = values[VIDX(x1, y0, z0)];
    float4 c101 = values[VIDX(x1, y0, z1)];
    float4 c110 = values[VIDX(x1, y1, z0)];
    float4 c111 = values[VIDX(x1, y1, z1)];
    #undef VIDX

    float4 c00 = lerp4(c000, c100, xd);
    float4 c01 = lerp4(c001, c101, xd);
    float4 c10 = lerp4(c010, c110, xd);
    float4 c11 = lerp4(c011, c111, xd);
    float4 c0  = lerp4(c00, c10, yd);
    float4 c1  = lerp4(c01, c11, yd);
    return lerp4(c0, c1, zd);
}

__device__ __forceinline__ void write_point_direct(const float4* __restrict__ values,
                                                   float4* __restrict__ out,
                                                   float x, float y, float z, unsigned p) {
    #pragma unroll
    for (int c = 0; c < 4; ++c)
        out[(size_t)p * 4 + c] = trilerp_point(values, x, y, z, c);
}

// ---------------- Pass 1a: coarse binning (64 buckets x 8 shards) ----------------
__global__ __launch_bounds__(256) void coarse_scatter(
    const float* __restrict__ points,
    unsigned* __restrict__ ccur,
    float4* __restrict__ crecs,
    const float4* __restrict__ values,
    float4* __restrict__ out,
    int n_points)
{
    __shared__ float4 stage[NC * CAPL];       // 49152 B
    __shared__ unsigned scnt[NC];

    for (int i = threadIdx.x; i < NC; i += 256) scnt[i] = 0;
    __syncthreads();

    int shard = blockIdx.x & (NSH - 1);       // XCD round-robin alignment
    int per = (n_points + SCAT_BLOCKS - 1) / SCAT_BLOCKS;
    int lo = blockIdx.x * per;
    int hi = min(lo + per, n_points);
    int lane = threadIdx.x & 63;
    int wid  = threadIdx.x >> 6;

    for (int base = lo; base < hi; base += 256) {
        int p = base + threadIdx.x;
        if (p < hi) {
            float x = points[p * 3 + 0] * 20.0f;   // 1/VOXEL_SIZE
            float y = points[p * 3 + 1] * 20.0f;
            float z = points[p * 3 + 2] * 20.0f;
            int cx = clampi((int)floorf(x), 0, DD - 1) >> 5;
            int cy = clampi((int)floorf(y), 0, DD - 1) >> 5;
            int cz = clampi((int)floorf(z), 0, DD - 1) >> 5;
            int c = (cx * NCX + cy) * NCX + cz;
            unsigned pos = atomicAdd(&scnt[c], 1u);
            if (pos < CAPL) {
                stage[c * CAPL + pos] = make_float4(x, y, z, __uint_as_float((unsigned)p));
            } else {
                // LDS stage overflow (statistically ~never): single global record
                unsigned g = atomicAdd(&ccur[(c * NSH + shard) * CCUR_STRIDE], 1u);
                if (g < CAPC) {
                    fvec4 r = { x, y, z, __uint_as_float((unsigned)p) };
                    __builtin_nontemporal_store(r,
                        (fvec4*)(crecs + ((size_t)(c * NSH + shard) * CAPC + g)));
                } else {
                    write_point_direct(values, out, x, y, z, (unsigned)p);
                }
            }
        }
        __syncthreads();
        // Flush buckets that reached the threshold; one wave per 16 buckets.
        for (int cb = wid * 16; cb < wid * 16 + 16; ++cb) {
            unsigned cnt = scnt[cb];
            if (cnt >= FLUSH_T) {
                unsigned wcnt = cnt < CAPL ? cnt : (unsigned)CAPL;
                unsigned gb = 0;
                if (lane == 0) gb = atomicAdd(&ccur[(cb * NSH + shard) * CCUR_STRIDE], wcnt);
                gb = __shfl(gb, 0);
                if (lane < (int)wcnt) {
                    float4 r = stage[cb * CAPL + lane];
                    unsigned g = gb + (unsigned)lane;
                    if (g < CAPC)
                        __builtin_nontemporal_store(*(fvec4*)&r,
                            (fvec4*)(crecs + ((size_t)(cb * NSH + shard) * CAPC + g)));
                    else
                        write_point_direct(values, out, r.x, r.y, r.z, __float_as_uint(r.w));
                }
                if (lane == 0) scnt[cb] = 0;
            }
        }
        __syncthreads();
    }
    // Final flush (any residue).
    for (int cb = wid * 16; cb < wid * 16 + 16; ++cb) {
        unsigned cnt = scnt[cb];
        if (cnt > 0) {
            unsigned wcnt = cnt < CAPL ? cnt : (unsigned)CAPL;
            unsigned gb = 0;
            if (lane == 0) gb = atomicAdd(&ccur[(cb * NSH + shard) * CCUR_STRIDE], wcnt);
            gb = __shfl(gb, 0);
            if (lane < (int)wcnt) {
                float4 r = stage[cb * CAPL + lane];
                unsigned g = gb + (unsigned)lane;
                if (g < CAPC)
                    __builtin_nontemporal_store(*(fvec4*)&r,
                        (fvec4*)(crecs + ((size_t)(cb * NSH + shard) * CAPC + g)));
                else
                    write_point_direct(values, out, r.x, r.y, r.z, __float_as_uint(r.w));
            }
        }
    }
}

// ---------------- Pass 1b: refine; one block per (coarse bucket, shard) ----------------
__global__ __launch_bounds__(256) void fine_scatter(
    const float4* __restrict__ crecs,
    const unsigned* __restrict__ ccur,
    unsigned* __restrict__ fcur,
    float4* __restrict__ frecs,
    const float4* __restrict__ values,
    float4* __restrict__ out)
{
    __shared__ float4 stage[NFPC * CAPL];
    __shared__ unsigned scnt[NFPC];

    for (int i = threadIdx.x; i < NFPC; i += 256) scnt[i] = 0;
    __syncthreads();

    int c = blockIdx.x >> 3;            // coarse bucket
    int s = blockIdx.x & 7;             // shard
    int cx = c >> 4, cy = (c >> 2) & 3, cz = c & 3;
    unsigned total = ccur[(c * NSH + s) * CCUR_STRIDE];
    if (total > CAPC) total = CAPC;
    const float4* src = crecs + (size_t)(c * NSH + s) * CAPC;
    int lane = threadIdx.x & 63;
    int wid  = threadIdx.x >> 6;

    for (unsigned base = 0; base < total; base += 256) {
        unsigned i = base + threadIdx.x;
        if (i < total) {
            float4 r = src[i];
            int fx = clampi((int)floorf(r.x), 0, DD - 1) >> 3;
            int fy = clampi((int)floorf(r.y), 0, DD - 1) >> 3;
            int fz = clampi((int)floorf(r.z), 0, DD - 1) >> 3;
            int lf = ((fx & 3) * 4 + (fy & 3)) * 4 + (fz & 3);
            unsigned pos = atomicAdd(&scnt[lf], 1u);
            if (pos < CAPL) {
                stage[lf * CAPL + pos] = r;
            } else {
                int fb = (fx * NBX + fy) * NBX + fz;
                unsigned g = atomicAdd(&fcur[fb * FCUR_STRIDE], 1u);
                if (g < CAPF)
                    __builtin_nontemporal_store(*(fvec4*)&r, (fvec4*)(frecs + (size_t)fb * CAPF + g));
                else
                    write_point_direct(values, out, r.x, r.y, r.z, __float_as_uint(r.w));
            }
        }
        __syncthreads();
        for (int lb = wid * 16; lb < wid * 16 + 16; ++lb) {
            unsigned cnt = scnt[lb];
            if (cnt >= FLUSH_T) {
                unsigned wcnt = cnt < CAPL ? cnt : (unsigned)CAPL;
                int fx = cx * 4 + (lb >> 4);
                int fy = cy * 4 + ((lb >> 2) & 3);
                int fz = cz * 4 + (lb & 3);
                int fb = (fx * NBX + fy) * NBX + fz;
                unsigned gb = 0;
                if (lane == 0) gb = atomicAdd(&fcur[fb * FCUR_STRIDE], wcnt);
                gb = __shfl(gb, 0);
                if (lane < (int)wcnt) {
                    float4 r = stage[lb * CAPL + lane];
                    unsigned g = gb + (unsigned)lane;
                    if (g < CAPF)
                        __builtin_nontemporal_store(*(fvec4*)&r, (fvec4*)(frecs + (size_t)fb * CAPF + g));
                    else
                        write_point_direct(values, out, r.x, r.y, r.z, __float_as_uint(r.w));
                }
                if (lane == 0) scnt[lb] = 0;
            }
        }
        __syncthreads();
    }
    // Final flush.
    for (int lb = wid * 16; lb < wid * 16 + 16; ++lb) {
        unsigned cnt = scnt[lb];
        if (cnt > 0) {
            unsigned wcnt = cnt < CAPL ? cnt : (unsigned)CAPL;
            int fx = cx * 4 + (lb >> 4);
            int fy = cy * 4 + ((lb >> 2) & 3);
            int fz = cz * 4 + (lb & 3);
            int fb = (fx * NBX + fy) * NBX + fz;
            unsigned gb = 0;
            if (lane == 0) gb = atomicAdd(&fcur[fb * FCUR_STRIDE], wcnt);
            gb = __shfl(gb, 0);
            if (lane < (int)wcnt) {
                float4 r = stage[lb * CAPL + lane];
                unsigned g = gb + (unsigned)lane;
                if (g < CAPF)
                    __builtin_nontemporal_store(*(fvec4*)&r, (fvec4*)(frecs + (size_t)fb * CAPF + g));
                else
                    write_point_direct(values, out, r.x, r.y, r.z, __float_as_uint(r.w));
            }
        }
    }
}

// ---------------- Pass 2: one block per fine bucket, LDS-staged halo ----------------
__global__ __launch_bounds__(256) void interp_kernel(
    const float4* __restrict__ recs,
    const unsigned* __restrict__ fcur,
    const float4* __restrict__ values,
    float4* __restrict__ out)
{
    __shared__ float4 sv[9 * 9 * 9 * 4];   // 46,656 B halo

    int b = blockIdx.x;
    int bz = b & 15, by = (b >> 4) & 15, bx = b >> 8;
    int X0 = bx << 3, Y0 = by << 3, Z0 = bz << 3;

    for (int e = threadIdx.x; e < 9 * 9 * 9 * 4; e += 256) {
        int v = e >> 2, cc = e & 3;
        int i = v / 81;
        int rr = v - i * 81;
        int j = rr / 9;
        int k = rr - j * 9;
        int gx = min(X0 + i, DD - 1);
        int gy = min(Y0 + j, DD - 1);
        int gz = min(Z0 + k, DD - 1);
        sv[e] = values[((((gx << 7) + gy) << 7) + gz) * 4 + cc];
    }
    __syncthreads();

    int c4 = threadIdx.x & 3;
    unsigned cnt = fcur[b * FCUR_STRIDE];
    if (cnt > CAPF) cnt = CAPF;
    const float4* rp = recs + (size_t)b * CAPF;

    #define SIDX(i, j, k) (((((i) * 9) + (j)) * 9 + (k)) * 4 + c4)
    for (unsigned j = threadIdx.x >> 2; j < cnt; j += 64) {
        float4 r = rp[j];
        float x = r.x, y = r.y, z = r.z;

        float fx = floorf(x), fy = floorf(y), fz = floorf(z);
        int x0 = clampi((int)fx, 0, DD - 1);
        int y0 = clampi((int)fy, 0, DD - 1);
        int z0 = clampi((int)fz, 0, DD - 1);
        float xd = x - (float)x0;
        float yd = y - (float)y0;
        float zd = z - (float)z0;

        int xl = x0 - X0, yl = y0 - Y0, zl = z0 - Z0;   // 0..7
        float4 c000 = sv[SIDX(xl,     yl,     zl    )];
        float4 c001 = sv[SIDX(xl,     yl,     zl + 1)];
        float4 c010 = sv[SIDX(xl,     yl + 1, zl    )];
        float4 c011 = sv[SIDX(xl,     yl + 1, zl + 1)];
        float4 c100 = sv[SIDX(xl + 1, yl,     zl    )];
        float4 c101 = sv[SIDX(xl + 1, yl,     zl + 1)];
        float4 c110 = sv[SIDX(xl + 1, yl + 1, zl    )];
        float4 c111 = sv[SIDX(xl + 1, yl + 1, zl + 1)];

        float4 c00 = lerp4(c000, c100, xd);
        float4 c01 = lerp4(c001, c101, xd);
        float4 c10 = lerp4(c010, c110, xd);
        float4 c11 = lerp4(c011, c111, xd);
        float4 c0  = lerp4(c00, c10, yd);
        float4 c1  = lerp4(c01, c11, yd);
        float4 res = lerp4(c0, c1, zd);

        unsigned idx = __float_as_uint(r.w);
        // CACHED store (v5): let L2/Infinity-Cache merge the two 64B halves
        // of each 128B out line; NT forced 64B partial HBM writes @0.95TB/s.
        out[(size_t)idx * 4 + c4] = res;
    }
    #undef SIDX
}

// ---------------- Tier-2 fallback: single-level direct scatter ----------------
__global__ __launch_bounds__(256) void direct_scatter(
    const float* __restrict__ points,
    unsigned* __restrict__ fcur,
    float4* __restrict__ frecs,
    const float4* __restrict__ values,
    float4* __restrict__ out,
    int n_points)
{
    int p = blockIdx.x * blockDim.x + threadIdx.x;
    if (p >= n_points) return;
    float x = points[p * 3 + 0] * 20.0f;
    float y = points[p * 3 + 1] * 20.0f;
    float z = points[p * 3 + 2] * 20.0f;
    int fx = clampi((int)floorf(x), 0, DD - 1) >> 3;
    int fy = clampi((int)floorf(y), 0, DD - 1) >> 3;
    int fz = clampi((int)floorf(z), 0, DD - 1) >> 3;
    int fb = (fx * NBX + fy) * NBX + fz;
    unsigned pos = atomicAdd(&fcur[fb * FCUR_STRIDE], 1u);
    if (pos < CAPF) {
        fvec4 r = { x, y, z, __uint_as_float((unsigned)p) };
        __builtin_nontemporal_store(r, (fvec4*)(frecs + (size_t)fb * CAPF + pos));
    } else {
        write_point_direct(values, out, x, y, z, (unsigned)p);
    }
}

// ---------------- Tier-3 fallback: v1 direct kernel ----------------
__global__ __launch_bounds__(256) void trilerp_kernel(
    const float* __restrict__ points,
    const float4* __restrict__ values,
    float4* __restrict__ out,
    int n_points)
{
    int t = blockIdx.x * blockDim.x + threadIdx.x;
    int p = t >> 2;
    int c4 = t & 3;
    if (p >= n_points) return;
    float x = points[p * 3 + 0] * 20.0f;
    float y = points[p * 3 + 1] * 20.0f;
    float z = points[p * 3 + 2] * 20.0f;
    out[t] = trilerp_point(values, x, y, z, c4);
}

extern "C" void kernel_launch(void* const* d_in, const int* in_sizes, int n_in,
                              void* d_out, int out_size, void* d_ws, size_t ws_size,
                              hipStream_t stream) {
    const float* points = (const float*)d_in[0];
    const float4* values = (const float4*)d_in[1];
    float4* out = (float4*)d_out;
    int n_points = in_sizes[0] / 3;

    const size_t ccur_b  = (size_t)NC * NSH * CCUR_STRIDE * sizeof(unsigned); // 32 KB
    const size_t fcur_b  = (size_t)NB * FCUR_STRIDE * sizeof(unsigned);       // 64 KB
    const size_t crecs_b = (size_t)NC * NSH * CAPC * sizeof(float4);          // ~36.7 MB
    const size_t frecs_b = (size_t)NB * CAPF * sizeof(float4);                // ~36.7 MB

    if (d_ws != nullptr && ws_size >= ccur_b + fcur_b + crecs_b + frecs_b) {
        // Tier 1: hierarchical binning.
        unsigned* ccur  = (unsigned*)d_ws;
        unsigned* fcur  = (unsigned*)((char*)d_ws + ccur_b);
        float4*   crecs = (float4*)((char*)d_ws + ccur_b + fcur_b);
        float4*   frecs = (float4*)((char*)d_ws + ccur_b + fcur_b + crecs_b);

        hipMemsetAsync(d_ws, 0, ccur_b + fcur_b, stream);
        coarse_scatter<<<SCAT_BLOCKS, 256, 0, stream>>>(points, ccur, crecs, values, out, n_points);
        fine_scatter<<<NC * NSH, 256, 0, stream>>>(crecs, ccur, fcur, frecs, values, out);
        interp_kernel<<<NB, 256, 0, stream>>>(frecs, fcur, values, out);
    } else if (d_ws != nullptr && ws_size >= fcur_b + frecs_b) {
        // Tier 2: single-level scatter (slower, proven).
        unsigned* fcur  = (unsigned*)d_ws;
        float4*   frecs = (float4*)((char*)d_ws + fcur_b);

        hipMemsetAsync(d_ws, 0, fcur_b, stream);
        int blocks = (n_points + 255) / 256;
        direct_scatter<<<blocks, 256, 0, stream>>>(points, fcur, frecs, values, out, n_points);
        interp_kernel<<<NB, 256, 0, stream>>>(frecs, fcur, values, out);
    } else {
        // Tier 3: original direct kernel.
        int total_threads = n_points * 4;
        int blocks = (total_threads + 255) / 256;
        trilerp_kernel<<<blocks, 256, 0, stream>>>(points, values, out, n_points);
    }
}

// Round 5
// 423.083 us; speedup vs baseline: 1.0133x; 1.0133x over previous
//
#include <hip/hip_runtime.h>

// Trilinear interpolation of 2M points into a 128x128x128x16 fp32 grid.
// v6: v5 pipeline with interp restructured for latency hiding:
//  - 2 blocks per fine bucket (channel-pairs): 35KB LDS -> 4 blocks/CU (was 3),
//    occupancy 30% -> ~50%.
//  - halo voxel stride padded to 48B: kills the measured 4.45M LDS bank
//    conflict cycles (old stride 64B aliased 16 quads onto 2 bank groups).
//  - rotated record loop with next-record prefetch (breaks dependent chain).
//  - bijective XCD-contiguous bucket swizzle for halo-staging L2 reuse.
//  - binning: smaller LDS stage (CAPL 36) -> 4 blocks/CU, 1024 scatter blocks.
// Results bit-identical to v1 (same op order everywhere).

#define DD 128
#define NBX 16                      // fine buckets per dim (8^3 voxels)
#define NB  (NBX * NBX * NBX)       // 4096 fine buckets
#define NCX 4                       // coarse buckets per dim (32^3 voxels)
#define NC  (NCX * NCX * NCX)       // 64 coarse buckets
#define NSH 8                       // coarse shards (blockIdx&7 ~ XCD)
#define NFPC 64                     // fine buckets per coarse (4^3)
#define CAPC 4480                   // per-(coarse,shard) capacity (mean 3906, +9 sigma)
#define CAPF 560                    // fine region capacity (mean 488, +3.2 sigma)
#define CAPL 36                     // LDS staging records per bucket
#define FLUSH_T 32                  // flush threshold (512B chunks)
#define CCUR_STRIDE 16              // coarse cursor padding (64B)
#define FCUR_STRIDE 16              // fine cursor padding (64B)
#define SCAT_BLOCKS 1024

typedef float fvec4 __attribute__((ext_vector_type(4)));

__device__ __forceinline__ float4 lerp4(float4 a, float4 b, float t) {
    return make_float4(fmaf(b.x - a.x, t, a.x),
                       fmaf(b.y - a.y, t, a.y),
                       fmaf(b.z - a.z, t, a.z),
                       fmaf(b.w - a.w, t, a.w));
}

__device__ __forceinline__ int clampi(int v, int lo, int hi) {
    return min(max(v, lo), hi);
}

// Direct (global-gather) path - identical op order to verified v1.
__device__ __forceinline__ float4 trilerp_point(const float4* __restrict__ values,
                                                float x, float y, float z, int c4) {
    float fx = floorf(x), fy = floorf(y), fz = floorf(z);
    int x0 = clampi((int)fx, 0, DD - 1);
    int y0 = clampi((int)fy, 0, DD - 1);
    int z0 = clampi((int)fz, 0, DD - 1);
    int x1 = min(x0 + 1, DD - 1);
    int y1 = min(y0 + 1, DD - 1);
    int z1 = min(z0 + 1, DD - 1);

    float xd = x - (float)x0;
    float yd = y - (float)y0;
    float zd = z - (float)z0;

    #define VIDX(xi, yi, zi) ((((((xi) << 7) + (yi)) << 7) + (zi)) * 4 + c4)
    float4 c000 = values[VIDX(x0, y0, z0)];
    float4 c001 = values[VIDX(x0, y0, z1)];
    float4 c010 = values[VIDX(x0, y1, z0)];
    float4 c011 = values[VIDX(x0, y1, z1)];
    float4 c100 = values[VIDX(x1, y0, z0)];
    float4 c101 = values[VIDX(x1, y0, z1)];
    float4 c110 = values[VIDX(x1, y1, z0)];
    float4 c111 = values[VIDX(x1, y1, z1)];
    #undef VIDX

    float4 c00 = lerp4(c000, c100, xd);
    float4 c01 = lerp4(c001, c101, xd);
    float4 c10 = lerp4(c010, c110, xd);
    float4 c11 = lerp4(c011, c111, xd);
    float4 c0  = lerp4(c00, c10, yd);
    float4 c1  = lerp4(c01, c11, yd);
    return lerp4(c0, c1, zd);
}

__device__ __forceinline__ void write_point_direct(const float4* __restrict__ values,
                                                   float4* __restrict__ out,
                                                   float x, float y, float z, unsigned p) {
    #pragma unroll
    for (int c = 0; c < 4; ++c)
        out[(size_t)p * 4 + c] = trilerp_point(values, x, y, z, c);
}

// ---------------- Pass 1a: coarse binning (64 buckets x 8 shards) ----------------
__global__ __launch_bounds__(256) void coarse_scatter(
    const float* __restrict__ points,
    unsigned* __restrict__ ccur,
    float4* __restrict__ crecs,
    const float4* __restrict__ values,
    float4* __restrict__ out,
    int n_points)
{
    __shared__ float4 stage[NC * CAPL];       // 36,864 B -> 4 blocks/CU
    __shared__ unsigned scnt[NC];

    for (int i = threadIdx.x; i < NC; i += 256) scnt[i] = 0;
    __syncthreads();

    int shard = blockIdx.x & (NSH - 1);
    int per = (n_points + SCAT_BLOCKS - 1) / SCAT_BLOCKS;
    int lo = blockIdx.x * per;
    int hi = min(lo + per, n_points);
    int lane = threadIdx.x & 63;
    int wid  = threadIdx.x >> 6;

    for (int base = lo; base < hi; base += 256) {
        int p = base + threadIdx.x;
        if (p < hi) {
            float x = points[p * 3 + 0] * 20.0f;   // 1/VOXEL_SIZE
            float y = points[p * 3 + 1] * 20.0f;
            float z = points[p * 3 + 2] * 20.0f;
            int cx = clampi((int)floorf(x), 0, DD - 1) >> 5;
            int cy = clampi((int)floorf(y), 0, DD - 1) >> 5;
            int cz = clampi((int)floorf(z), 0, DD - 1) >> 5;
            int c = (cx * NCX + cy) * NCX + cz;
            unsigned pos = atomicAdd(&scnt[c], 1u);
            if (pos < CAPL) {
                stage[c * CAPL + pos] = make_float4(x, y, z, __uint_as_float((unsigned)p));
            } else {
                unsigned g = atomicAdd(&ccur[(c * NSH + shard) * CCUR_STRIDE], 1u);
                if (g < CAPC) {
                    fvec4 r = { x, y, z, __uint_as_float((unsigned)p) };
                    __builtin_nontemporal_store(r,
                        (fvec4*)(crecs + ((size_t)(c * NSH + shard) * CAPC + g)));
                } else {
                    write_point_direct(values, out, x, y, z, (unsigned)p);
                }
            }
        }
        __syncthreads();
        for (int cb = wid * 16; cb < wid * 16 + 16; ++cb) {
            unsigned cnt = scnt[cb];
            if (cnt >= FLUSH_T) {
                unsigned wcnt = cnt < CAPL ? cnt : (unsigned)CAPL;
                unsigned gb = 0;
                if (lane == 0) gb = atomicAdd(&ccur[(cb * NSH + shard) * CCUR_STRIDE], wcnt);
                gb = __shfl(gb, 0);
                if (lane < (int)wcnt) {
                    float4 r = stage[cb * CAPL + lane];
                    unsigned g = gb + (unsigned)lane;
                    if (g < CAPC)
                        __builtin_nontemporal_store(*(fvec4*)&r,
                            (fvec4*)(crecs + ((size_t)(cb * NSH + shard) * CAPC + g)));
                    else
                        write_point_direct(values, out, r.x, r.y, r.z, __float_as_uint(r.w));
                }
                if (lane == 0) scnt[cb] = 0;
            }
        }
        __syncthreads();
    }
    for (int cb = wid * 16; cb < wid * 16 + 16; ++cb) {
        unsigned cnt = scnt[cb];
        if (cnt > 0) {
            unsigned wcnt = cnt < CAPL ? cnt : (unsigned)CAPL;
            unsigned gb = 0;
            if (lane == 0) gb = atomicAdd(&ccur[(cb * NSH + shard) * CCUR_STRIDE], wcnt);
            gb = __shfl(gb, 0);
            if (lane < (int)wcnt) {
                float4 r = stage[cb * CAPL + lane];
                unsigned g = gb + (unsigned)lane;
                if (g < CAPC)
                    __builtin_nontemporal_store(*(fvec4*)&r,
                        (fvec4*)(crecs + ((size_t)(cb * NSH + shard) * CAPC + g)));
                else
                    write_point_direct(values, out, r.x, r.y, r.z, __float_as_uint(r.w));
            }
        }
    }
}

// ---------------- Pass 1b: refine; one block per (coarse bucket, shard) ----------------
__global__ __launch_bounds__(256) void fine_scatter(
    const float4* __restrict__ crecs,
    const unsigned* __restrict__ ccur,
    unsigned* __restrict__ fcur,
    float4* __restrict__ frecs,
    const float4* __restrict__ values,
    float4* __restrict__ out)
{
    __shared__ float4 stage[NFPC * CAPL];     // 36,864 B
    __shared__ unsigned scnt[NFPC];

    for (int i = threadIdx.x; i < NFPC; i += 256) scnt[i] = 0;
    __syncthreads();

    int c = blockIdx.x >> 3;            // coarse bucket
    int s = blockIdx.x & 7;             // shard
    int cx = c >> 4, cy = (c >> 2) & 3, cz = c & 3;
    unsigned total = ccur[(c * NSH + s) * CCUR_STRIDE];
    if (total > CAPC) total = CAPC;
    const float4* src = crecs + (size_t)(c * NSH + s) * CAPC;
    int lane = threadIdx.x & 63;
    int wid  = threadIdx.x >> 6;

    for (unsigned base = 0; base < total; base += 256) {
        unsigned i = base + threadIdx.x;
        if (i < total) {
            float4 r = src[i];
            int fx = clampi((int)floorf(r.x), 0, DD - 1) >> 3;
            int fy = clampi((int)floorf(r.y), 0, DD - 1) >> 3;
            int fz = clampi((int)floorf(r.z), 0, DD - 1) >> 3;
            int lf = ((fx & 3) * 4 + (fy & 3)) * 4 + (fz & 3);
            unsigned pos = atomicAdd(&scnt[lf], 1u);
            if (pos < CAPL) {
                stage[lf * CAPL + pos] = r;
            } else {
                int fb = (fx * NBX + fy) * NBX + fz;
                unsigned g = atomicAdd(&fcur[fb * FCUR_STRIDE], 1u);
                if (g < CAPF)
                    __builtin_nontemporal_store(*(fvec4*)&r, (fvec4*)(frecs + (size_t)fb * CAPF + g));
                else
                    write_point_direct(values, out, r.x, r.y, r.z, __float_as_uint(r.w));
            }
        }
        __syncthreads();
        for (int lb = wid * 16; lb < wid * 16 + 16; ++lb) {
            unsigned cnt = scnt[lb];
            if (cnt >= FLUSH_T) {
                unsigned wcnt = cnt < CAPL ? cnt : (unsigned)CAPL;
                int fx = cx * 4 + (lb >> 4);
                int fy = cy * 4 + ((lb >> 2) & 3);
                int fz = cz * 4 + (lb & 3);
                int fb = (fx * NBX + fy) * NBX + fz;
                unsigned gb = 0;
                if (lane == 0) gb = atomicAdd(&fcur[fb * FCUR_STRIDE], wcnt);
                gb = __shfl(gb, 0);
                if (lane < (int)wcnt) {
                    float4 r = stage[lb * CAPL + lane];
                    unsigned g = gb + (unsigned)lane;
                    if (g < CAPF)
                        __builtin_nontemporal_store(*(fvec4*)&r, (fvec4*)(frecs + (size_t)fb * CAPF + g));
                    else
                        write_point_direct(values, out, r.x, r.y, r.z, __float_as_uint(r.w));
                }
                if (lane == 0) scnt[lb] = 0;
            }
        }
        __syncthreads();
    }
    for (int lb = wid * 16; lb < wid * 16 + 16; ++lb) {
        unsigned cnt = scnt[lb];
        if (cnt > 0) {
            unsigned wcnt = cnt < CAPL ? cnt : (unsigned)CAPL;
            int fx = cx * 4 + (lb >> 4);
            int fy = cy * 4 + ((lb >> 2) & 3);
            int fz = cz * 4 + (lb & 3);
            int fb = (fx * NBX + fy) * NBX + fz;
            unsigned gb = 0;
            if (lane == 0) gb = atomicAdd(&fcur[fb * FCUR_STRIDE], wcnt);
            gb = __shfl(gb, 0);
            if (lane < (int)wcnt) {
                float4 r = stage[lb * CAPL + lane];
                unsigned g = gb + (unsigned)lane;
                if (g < CAPF)
                    __builtin_nontemporal_store(*(fvec4*)&r, (fvec4*)(frecs + (size_t)fb * CAPF + g));
                else
                    write_point_direct(values, out, r.x, r.y, r.z, __float_as_uint(r.w));
            }
        }
    }
}

// ---------------- Pass 2: two blocks per fine bucket (channel pairs) ----------------
// LDS: 9^3 voxels x 2 channel-quads, padded to 3 float4/voxel (48B) so bank
// index 12*voxel mod 32 cycles 8 residues (~2-way, free) instead of 2 (8-way).
__global__ __launch_bounds__(256) void interp_kernel(
    const float4* __restrict__ recs,
    const unsigned* __restrict__ fcur,
    const float4* __restrict__ values,
    float4* __restrict__ out)
{
    __shared__ float4 sv[9 * 9 * 9 * 3];   // 34,992 B -> 4 blocks/CU

    // Bijective XCD swizzle: 8192 % 8 == 0; each XCD gets a contiguous
    // 512-bucket range (both halves of a bucket stay on one XCD).
    int swz = ((int)blockIdx.x & 7) * (2 * NB / 8) + ((int)blockIdx.x >> 3);
    int b    = swz >> 1;                   // fine bucket
    int half = swz & 1;                    // channel pair: c4 in {2*half, 2*half+1}
    int bz = b & 15, by = (b >> 4) & 15, bx = b >> 8;
    int X0 = bx << 3, Y0 = by << 3, Z0 = bz << 3;

    // Stage this block's 2 channel-quads of the 9x9x9 halo.
    for (int e = threadIdx.x; e < 9 * 9 * 9 * 2; e += 256) {
        int v = e >> 1, q = e & 1;
        int i = v / 81;
        int rr = v - i * 81;
        int j = rr / 9;
        int k = rr - j * 9;
        int gx = min(X0 + i, DD - 1);
        int gy = min(Y0 + j, DD - 1);
        int gz = min(Z0 + k, DD - 1);
        sv[v * 3 + q] = values[((((gx << 7) + gy) << 7) + gz) * 4 + (half << 1) + q];
    }
    __syncthreads();

    int q = threadIdx.x & 1;               // which quad of the pair
    int c4 = (half << 1) | q;              // output channel-quad
    unsigned cnt = fcur[b * FCUR_STRIDE];
    if (cnt > CAPF) cnt = CAPF;
    const float4* rp = recs + (size_t)b * CAPF;

    #define SIDX(i, j, k) (((((i) * 9) + (j)) * 9 + (k)) * 3 + q)
    unsigned j = threadIdx.x >> 1;         // 2 lanes per record, stride 128
    float4 r = make_float4(0.f, 0.f, 0.f, 0.f);
    if (j < cnt) r = rp[j];
    while (j < cnt) {
        unsigned jn = j + 128;
        float4 rn = make_float4(0.f, 0.f, 0.f, 0.f);
        if (jn < cnt) rn = rp[jn];         // prefetch next record

        float x = r.x, y = r.y, z = r.z;
        float fx = floorf(x), fy = floorf(y), fz = floorf(z);
        int x0 = clampi((int)fx, 0, DD - 1);
        int y0 = clampi((int)fy, 0, DD - 1);
        int z0 = clampi((int)fz, 0, DD - 1);
        float xd = x - (float)x0;
        float yd = y - (float)y0;
        float zd = z - (float)z0;

        int xl = x0 - X0, yl = y0 - Y0, zl = z0 - Z0;   // 0..7
        float4 c000 = sv[SIDX(xl,     yl,     zl    )];
        float4 c001 = sv[SIDX(xl,     yl,     zl + 1)];
        float4 c010 = sv[SIDX(xl,     yl + 1, zl    )];
        float4 c011 = sv[SIDX(xl,     yl + 1, zl + 1)];
        float4 c100 = sv[SIDX(xl + 1, yl,     zl    )];
        float4 c101 = sv[SIDX(xl + 1, yl,     zl + 1)];
        float4 c110 = sv[SIDX(xl + 1, yl + 1, zl    )];
        float4 c111 = sv[SIDX(xl + 1, yl + 1, zl + 1)];

        float4 c00 = lerp4(c000, c100, xd);
        float4 c01 = lerp4(c001, c101, xd);
        float4 c10 = lerp4(c010, c110, xd);
        float4 c11 = lerp4(c011, c111, xd);
        float4 c0  = lerp4(c00, c10, yd);
        float4 c1  = lerp4(c01, c11, yd);
        float4 res = lerp4(c0, c1, zd);

        unsigned idx = __float_as_uint(r.w);
        out[(size_t)idx * 4 + c4] = res;   // 2 lanes merge into one 32B req; pairwise 64B

        r = rn; j = jn;
    }
    #undef SIDX
}

// ---------------- Tier-2 fallback: single-level direct scatter ----------------
__global__ __launch_bounds__(256) void direct_scatter(
    const float* __restrict__ points,
    unsigned* __restrict__ fcur,
    float4* __restrict__ frecs,
    const float4* __restrict__ values,
    float4* __restrict__ out,
    int n_points)
{
    int p = blockIdx.x * blockDim.x + threadIdx.x;
    if (p >= n_points) return;
    float x = points[p * 3 + 0] * 20.0f;
    float y = points[p * 3 + 1] * 20.0f;
    float z = points[p * 3 + 2] * 20.0f;
    int fx = clampi((int)floorf(x), 0, DD - 1) >> 3;
    int fy = clampi((int)floorf(y), 0, DD - 1) >> 3;
    int fz = clampi((int)floorf(z), 0, DD - 1) >> 3;
    int fb = (fx * NBX + fy) * NBX + fz;
    unsigned pos = atomicAdd(&fcur[fb * FCUR_STRIDE], 1u);
    if (pos < CAPF) {
        fvec4 r = { x, y, z, __uint_as_float((unsigned)p) };
        __builtin_nontemporal_store(r, (fvec4*)(frecs + (size_t)fb * CAPF + pos));
    } else {
        write_point_direct(values, out, x, y, z, (unsigned)p);
    }
}

// ---------------- Tier-3 fallback: v1 direct kernel ----------------
__global__ __launch_bounds__(256) void trilerp_kernel(
    const float* __restrict__ points,
    const float4* __restrict__ values,
    float4* __restrict__ out,
    int n_points)
{
    int t = blockIdx.x * blockDim.x + threadIdx.x;
    int p = t >> 2;
    int c4 = t & 3;
    if (p >= n_points) return;
    float x = points[p * 3 + 0] * 20.0f;
    float y = points[p * 3 + 1] * 20.0f;
    float z = points[p * 3 + 2] * 20.0f;
    out[t] = trilerp_point(values, x, y, z, c4);
}

extern "C" void kernel_launch(void* const* d_in, const int* in_sizes, int n_in,
                              void* d_out, int out_size, void* d_ws, size_t ws_size,
                              hipStream_t stream) {
    const float* points = (const float*)d_in[0];
    const float4* values = (const float4*)d_in[1];
    float4* out = (float4*)d_out;
    int n_points = in_sizes[0] / 3;

    const size_t ccur_b  = (size_t)NC * NSH * CCUR_STRIDE * sizeof(unsigned); // 32 KB
    const size_t fcur_b  = (size_t)NB * FCUR_STRIDE * sizeof(unsigned);       // 256 KB
    const size_t crecs_b = (size_t)NC * NSH * CAPC * sizeof(float4);          // ~36.7 MB
    const size_t frecs_b = (size_t)NB * CAPF * sizeof(float4);                // ~36.7 MB

    if (d_ws != nullptr && ws_size >= ccur_b + fcur_b + crecs_b + frecs_b) {
        unsigned* ccur  = (unsigned*)d_ws;
        unsigned* fcur  = (unsigned*)((char*)d_ws + ccur_b);
        float4*   crecs = (float4*)((char*)d_ws + ccur_b + fcur_b);
        float4*   frecs = (float4*)((char*)d_ws + ccur_b + fcur_b + crecs_b);

        hipMemsetAsync(d_ws, 0, ccur_b + fcur_b, stream);
        coarse_scatter<<<SCAT_BLOCKS, 256, 0, stream>>>(points, ccur, crecs, values, out, n_points);
        fine_scatter<<<NC * NSH, 256, 0, stream>>>(crecs, ccur, fcur, frecs, values, out);
        interp_kernel<<<2 * NB, 256, 0, stream>>>(frecs, fcur, values, out);
    } else if (d_ws != nullptr && ws_size >= fcur_b + frecs_b) {
        unsigned* fcur  = (unsigned*)d_ws;
        float4*   frecs = (float4*)((char*)d_ws + fcur_b);

        hipMemsetAsync(d_ws, 0, fcur_b, stream);
        int blocks = (n_points + 255) / 256;
        direct_scatter<<<blocks, 256, 0, stream>>>(points, fcur, frecs, values, out, n_points);
        interp_kernel<<<2 * NB, 256, 0, stream>>>(frecs, fcur, values, out);
    } else {
        int total_threads = n_points * 4;
        int blocks = (total_threads + 255) / 256;
        trilerp_kernel<<<blocks, 256, 0, stream>>>(points, values, out, n_points);
    }
}

// Round 6
// 408.179 us; speedup vs baseline: 1.0503x; 1.0365x over previous
//
#include <hip/hip_runtime.h>

// Trilinear interpolation of 2M points into a 128x128x128x16 fp32 grid.
// v7: back to the v1 direct structure (sequential out-writes, random reads —
// reads proved 3.5x faster than the random-write wall), but with the gather
// request count HALVED via z-pair octets:
//   8 lanes per point: lane (q,s), q=channel-quad 0..3, s=z-side 0..1.
//   For each of the 4 (x,y) corners, the octet's 8 loads cover
//   values[x][y][z0][0..3] ++ values[x][y][z0+1][0..3] = one CONTIGUOUS,
//   fully-used 128B request (vs v1: two 64B requests each wasting half a line).
//   4 requests/point instead of 8. The 134MB grid lives in the 256MB Infinity
//   Cache; v1's 3.46TB/s @ 16M requests looked request-rate-limited, so
//   halving requests should raise effective gather throughput.
// Final zd-lerp crosses the z-side lanes via __shfl_xor(4). Op order is
// exactly v1's -> bit-identical results.

#define DD 128
#define HH 128
#define WW 128

__device__ __forceinline__ float4 lerp4(float4 a, float4 b, float t) {
    return make_float4(fmaf(b.x - a.x, t, a.x),
                       fmaf(b.y - a.y, t, a.y),
                       fmaf(b.z - a.z, t, a.z),
                       fmaf(b.w - a.w, t, a.w));
}

__global__ __launch_bounds__(256) void trilerp_octet(
    const float* __restrict__ points,
    const float4* __restrict__ values,
    float4* __restrict__ out,
    int n_points)
{
    int t = blockIdx.x * blockDim.x + threadIdx.x;
    int p = t >> 3;            // point index (8 lanes per point)
    if (p >= n_points) return;
    int e = t & 7;
    int q = e & 3;             // channel quad (float4 index within the voxel)
    int s = e >> 2;            // z-side: 0 -> z0, 1 -> z1

    float x = points[p * 3 + 0] * 20.0f;   // 1/VOXEL_SIZE = 20
    float y = points[p * 3 + 1] * 20.0f;
    float z = points[p * 3 + 2] * 20.0f;

    float fx = floorf(x), fy = floorf(y), fz = floorf(z);
    int x0 = min(max((int)fx, 0), DD - 1);
    int y0 = min(max((int)fy, 0), HH - 1);
    int z0 = min(max((int)fz, 0), WW - 1);
    int x1 = min(x0 + 1, DD - 1);
    int y1 = min(y0 + 1, HH - 1);
    int z1 = min(z0 + 1, WW - 1);

    float xd = x - (float)x0;
    float yd = y - (float)y0;
    float zd = z - (float)z0;

    int zs = s ? z1 : z0;

    // Octet lane addresses for one (xi,yi): zs in {z0,z0+1}, q in 0..3
    // -> 8 consecutive float4s = one contiguous 128B request (z0<127).
    #define VIDX(xi, yi) ((((((xi) << 7) + (yi)) << 7) + zs) * 4 + q)
    float4 A = values[VIDX(x0, y0)];   // c00s
    float4 B = values[VIDX(x0, y1)];   // c01s
    float4 C = values[VIDX(x1, y0)];   // c10s
    float4 D = values[VIDX(x1, y1)];   // c11s
    #undef VIDX

    // Same op order as v1:
    //  s=0 lane: u=c00, v=c10, w=c0.   s=1 lane: u=c01, v=c11, w=c1.
    float4 u = lerp4(A, C, xd);
    float4 v = lerp4(B, D, xd);
    float4 w = lerp4(u, v, yd);

    // Exchange c0/c1 across the z-side lanes (lane ^ 4). All 8 lanes active.
    float4 o4;
    o4.x = __shfl_xor(w.x, 4);
    o4.y = __shfl_xor(w.y, 4);
    o4.z = __shfl_xor(w.z, 4);
    o4.w = __shfl_xor(w.w, 4);

    if (s == 0) {
        float4 res = lerp4(w, o4, zd);   // lerp4(c0, c1, zd) — v1's final op
        out[(size_t)p * 4 + q] = res;    // lanes 0-3 of octet: contiguous 64B;
                                         // adjacent octets complete 128B lines
    }
}

extern "C" void kernel_launch(void* const* d_in, const int* in_sizes, int n_in,
                              void* d_out, int out_size, void* d_ws, size_t ws_size,
                              hipStream_t stream) {
    const float* points = (const float*)d_in[0];
    const float4* values = (const float4*)d_in[1];
    float4* out = (float4*)d_out;

    int n_points = in_sizes[0] / 3;
    long long total_threads = (long long)n_points * 8;
    int blocks = (int)((total_threads + 255) / 256);

    trilerp_octet<<<blocks, 256, 0, stream>>>(points, values, out, n_points);
}